// Round 9
// baseline (613.724 us; speedup 1.0000x reference)
//
#include <hip/hip_runtime.h>
#include <hip/hip_bf16.h>
#include <stdint.h>

#define M_DIM 8192
#define K_DIM 2048
#define N_DIM 4096
#define BT 256
#define NT_M (M_DIM / BT)   // 32 m-tiles
#define NT_N (N_DIM / BT)   // 16 n-tiles
#define NKT (K_DIM / 64)    // 32 K-tiles of BK=64

typedef __hip_bfloat16 bf16;
typedef __attribute__((ext_vector_type(8))) short bf16x8;
typedef __attribute__((ext_vector_type(4))) float floatx4;

// ---------------- Kernel 1: 256x256 8-phase pipelined GEMM (C^T) + GN + min ----
// Round-5 skeleton (phases/barriers/frag-reads/gates identical; best 116.5us)
// with CONVERT FUSED INTO STAGING: global_load_lds replaced by reg-staged
// fp32 loads (LD4, issued one phase ahead, ping-pong banks fA*/fB*) ->
// VMW(4) wave-local wait -> cvt to bf16 -> 2x ds_write_b128 (CW). Writes are
// issued BEFORE each phase's frag reads so the counted lgkm gates (4/8/0/-)
// drain them; every buffer is fully written+drained >=1 barrier before its
// first consumer read (k1 by p3-gate < p4-barrier; k2 by p7-gate < p8-barrier).
// No cross-wave vmcnt rendezvous remains (loads land in own-wave registers).

#define BARX() __builtin_amdgcn_s_barrier()
#define SB0()  __builtin_amdgcn_sched_barrier(0)
#define LGKMW(n) do { asm volatile("s_waitcnt lgkmcnt(" n ")" ::: "memory"); \
                      __builtin_amdgcn_sched_barrier(0); } while (0)
#define VMW(n)   do { asm volatile("s_waitcnt vmcnt(" n ")" ::: "memory"); \
                      __builtin_amdgcn_sched_barrier(0); } while (0)

// load one half-tile slice (this wave's 16 rows x 64k, fp32): 4 dwordx4
#define LD4(gp, kt, hh, R0, R1, R2, R3) do { \
  const float* _p = (gp) + ((size_t)(hh) * 128) * K_DIM + (size_t)(kt) * 64; \
  R0 = *(const float4*)(_p); \
  R1 = *(const float4*)(_p + 4); \
  R2 = *(const float4*)(_p + 8 * K_DIM); \
  R3 = *(const float4*)(_p + 8 * K_DIM + 4); \
} while (0)

// convert one staged half-tile slice to bf16 and write to LDS (same layout
// as the old global_load_lds dest: base + lane*16B, two 512-elem row-groups)
#define CW(dp, hh, R0, R1, R2, R3) do { \
  union { bf16 h[8]; bf16x8 v; } _o0, _o1; \
  _o0.h[0] = __float2bfloat16(R0.x); _o0.h[1] = __float2bfloat16(R0.y); \
  _o0.h[2] = __float2bfloat16(R0.z); _o0.h[3] = __float2bfloat16(R0.w); \
  _o0.h[4] = __float2bfloat16(R1.x); _o0.h[5] = __float2bfloat16(R1.y); \
  _o0.h[6] = __float2bfloat16(R1.z); _o0.h[7] = __float2bfloat16(R1.w); \
  _o1.h[0] = __float2bfloat16(R2.x); _o1.h[1] = __float2bfloat16(R2.y); \
  _o1.h[2] = __float2bfloat16(R2.z); _o1.h[3] = __float2bfloat16(R2.w); \
  _o1.h[4] = __float2bfloat16(R3.x); _o1.h[5] = __float2bfloat16(R3.y); \
  _o1.h[6] = __float2bfloat16(R3.z); _o1.h[7] = __float2bfloat16(R3.w); \
  *(bf16x8*)((dp) + (hh) * 8192 + lane * 8) = _o0.v; \
  *(bf16x8*)((dp) + (hh) * 8192 + 512 + lane * 8) = _o1.v; \
} while (0)

// frag reads (8-per A-half, 4-per B-pair); swk* carries the XOR bank swizzle
#define RD_A0(rp) do { _Pragma("unroll") for (int i2 = 0; i2 < 4; ++i2) { \
  af0[i2][0] = *(const bf16x8*)((rp) + (i2 * 16) * 64 + swk0); \
  af0[i2][1] = *(const bf16x8*)((rp) + (i2 * 16) * 64 + swk1); } } while (0)
#define RD_A1(rp) do { _Pragma("unroll") for (int i2 = 0; i2 < 4; ++i2) { \
  af1[i2][0] = *(const bf16x8*)((rp) + (64 + i2 * 16) * 64 + swk0); \
  af1[i2][1] = *(const bf16x8*)((rp) + (64 + i2 * 16) * 64 + swk1); } } while (0)
#define RD_B01(rp, B) do { _Pragma("unroll") for (int j2 = 0; j2 < 2; ++j2) { \
  B[j2][0] = *(const bf16x8*)((rp) + (j2 * 16) * 64 + swk0); \
  B[j2][1] = *(const bf16x8*)((rp) + (j2 * 16) * 64 + swk1); } } while (0)
#define RD_B23(rp) do { _Pragma("unroll") for (int j2 = 0; j2 < 2; ++j2) { \
  b23[j2][0] = *(const bf16x8*)((rp) + ((2 + j2) * 16) * 64 + swk0); \
  b23[j2][1] = *(const bf16x8*)((rp) + ((2 + j2) * 16) * 64 + swk1); } } while (0)

#define MFQ(i0, j0, A, B) do { \
  __builtin_amdgcn_s_setprio(1); \
  _Pragma("unroll") for (int i2 = 0; i2 < 4; ++i2) \
  _Pragma("unroll") for (int j2 = 0; j2 < 2; ++j2) { \
    acc[(i0) + i2][(j0) + j2] = __builtin_amdgcn_mfma_f32_16x16x32_bf16( \
        A[i2][0], B[j2][0], acc[(i0) + i2][(j0) + j2], 0, 0, 0); \
    acc[(i0) + i2][(j0) + j2] = __builtin_amdgcn_mfma_f32_16x16x32_bf16( \
        A[i2][1], B[j2][1], acc[(i0) + i2][(j0) + j2], 0, 0, 0); } \
  __builtin_amdgcn_s_setprio(0); } while (0)

__global__ __launch_bounds__(512, 2) void gemm_gn_min(
    const float* __restrict__ x, const float* __restrict__ W,
    const float* __restrict__ bgemm, float* __restrict__ pmin) {
  __shared__ bf16 sA[32768];   // [2][256*64] W tiles (A-operand), 64 KiB
  __shared__ bf16 sB[32768];   // [2][256*64] x tiles (B-operand), 64 KiB

  const int tid  = threadIdx.x;
  const int lane = tid & 63;
  const int wid  = tid >> 6;      // 0..7
  const int wr   = wid >> 2;      // n-half (0..1): rows wr*128..+127
  const int wc   = wid & 3;       // m-quarter (0..3): cols wc*64..+63
  const int q    = lane >> 4;     // quad 0..3
  const int c    = lane & 15;

  const int mTile = blockIdx.x & (NT_M - 1);
  const int nTile = blockIdx.x >> 5;
  const int mBase = mTile * BT;
  const int nBase = nTile * BT;

  // staging map: lane -> (row-in-8-chunk, xor-swizzled k-chunk on GLOBAL col)
  const int ldRow = lane >> 3;
  const int swz   = ((lane & 7) ^ ldRow) * 8;
  // read-side swizzle (chunk = (ks*4+q) ^ (row&7); row&7 == c&7 here)
  const int swk0 = (q ^ (c & 7)) * 8;
  const int swk1 = ((4 + q) ^ (c & 7)) * 8;

  // per-wave fp32 staging bases (wave covers rows wid*16 + ldRow + {0,8})
  const float* gAf = W + (size_t)(nBase + wid * 16 + ldRow) * K_DIM + swz;
  const float* gBf = x + (size_t)(mBase + wid * 16 + ldRow) * K_DIM + swz;
  // per-wave LDS dest bases: buf0 (dA0/dB0) and buf1 (dA1/dB1)
  bf16* dA0 = sA + wid * 1024;
  bf16* dB0 = sB + wid * 1024;
  bf16* dA1 = dA0 + 16384;
  bf16* dB1 = dB0 + 16384;
  // per-lane LDS read bases
  const bf16* rA0 = sA + (wr * 128 + c) * 64;
  const bf16* rA1 = rA0 + 16384;
  const bf16* rB0 = sB + (wc * 64 + c) * 64;
  const bf16* rB1 = rB0 + 16384;

  floatx4 acc[8][4];
#pragma unroll
  for (int i = 0; i < 8; ++i)
#pragma unroll
    for (int j = 0; j < 4; ++j) acc[i][j] = (floatx4){0.f, 0.f, 0.f, 0.f};

  // frag register banks (unchanged) + fp32 staging ping-pong banks fA*/fB*
  bf16x8 af0[4][2], af1[4][2], b01a[2][2], b01b[2][2], b23[2][2];
  float4 fA0, fA1, fA2, fA3, fB0, fB1, fB2, fB3;

  // ---- prologue: stage k0 all 4 halves + k1.Bh0; leave k1.Bh1 loads (4) in
  // flight in bank A; drain writes; publish barrier; read k0 frags (12).
  LD4(gBf, 0, 0, fA0, fA1, fA2, fA3);
  LD4(gBf, 0, 1, fB0, fB1, fB2, fB3);
  VMW("4"); CW(dB0, 0, fA0, fA1, fA2, fA3);
  LD4(gAf, 0, 0, fA0, fA1, fA2, fA3);
  VMW("4"); CW(dB0, 1, fB0, fB1, fB2, fB3);
  LD4(gAf, 0, 1, fB0, fB1, fB2, fB3);
  VMW("4"); CW(dA0, 0, fA0, fA1, fA2, fA3);
  LD4(gBf, 1, 0, fA0, fA1, fA2, fA3);
  VMW("4"); CW(dA0, 1, fB0, fB1, fB2, fB3);
  VMW("0"); CW(dB1, 0, fA0, fA1, fA2, fA3);
  LD4(gBf, 1, 1, fA0, fA1, fA2, fA3);   // k1.Bh1 -> A (4 outstanding)
  LGKMW("0");
  BARX();
  RD_A0(rA0); RD_B01(rB0, b01a); SB0();

  // ---- main loop: iter i computes k0=2i (buf0, p1-4) and k1=2i+1 (buf1,
  // p5-8). One half-tile staged per phase: W(phase) / L(next half):
  //  p1: W k1.Bh1 / L k1.Ah0   p2: W k1.Ah0 / L k1.Ah1
  //  p3: W k1.Ah1 / L k2.Bh0   p4: W k2.Bh0 / L k2.Bh1
  //  p5: W k2.Bh1 / L k2.Ah0   p6: W k2.Ah0 / L k2.Ah1
  //  p7: W k2.Ah1 / L k3.Bh0   p8: W k3.Bh0 / L k3.Bh1
  // ds_writes precede frag reads -> gates drain them; k1 publish complete by
  // p3-gate < p4 BARX; k2 by p7-gate < p8 BARX. VMW(4) waits own prev loads.
#pragma unroll 1
  for (int i = 0; i < NKT / 2 - 1; ++i) {
    const int k1 = 2 * i + 1, k2 = 2 * i + 2, k3 = 2 * i + 3;
    // p1
    LD4(gAf, k1, 0, fB0, fB1, fB2, fB3); VMW("4");
    CW(dB1, 1, fA0, fA1, fA2, fA3);
    RD_B23(rB0); SB0();
    BARX(); LGKMW("4"); MFQ(0, 0, af0, b01a);
    // p2
    LD4(gAf, k1, 1, fA0, fA1, fA2, fA3); VMW("4");
    CW(dA1, 0, fB0, fB1, fB2, fB3);
    RD_A1(rA0); SB0();
    BARX(); LGKMW("8"); MFQ(0, 2, af0, b23);
    // p3
    LD4(gBf, k2, 0, fB0, fB1, fB2, fB3); VMW("4");
    CW(dA1, 1, fA0, fA1, fA2, fA3);
    BARX(); LGKMW("0"); MFQ(4, 2, af1, b23);
    // p4: buf1 (k1) published; cross-buffer read-ahead after the barrier
    LD4(gBf, k2, 1, fA0, fA1, fA2, fA3); VMW("4");
    CW(dB0, 0, fB0, fB1, fB2, fB3);
    BARX();
    RD_A0(rA1); RD_B01(rB1, b01b); SB0();
    MFQ(4, 0, af1, b01a);
    // p5
    LD4(gAf, k2, 0, fB0, fB1, fB2, fB3); VMW("4");
    CW(dB0, 1, fA0, fA1, fA2, fA3);
    RD_B23(rB1); SB0();
    BARX(); LGKMW("4"); MFQ(0, 0, af0, b01b);
    // p6
    LD4(gAf, k2, 1, fA0, fA1, fA2, fA3); VMW("4");
    CW(dA0, 0, fB0, fB1, fB2, fB3);
    RD_A1(rA1); SB0();
    BARX(); LGKMW("8"); MFQ(0, 2, af0, b23);
    // p7
    LD4(gBf, k3, 0, fB0, fB1, fB2, fB3); VMW("4");
    CW(dA0, 1, fA0, fA1, fA2, fA3);
    BARX(); LGKMW("0"); MFQ(4, 2, af1, b23);
    // p8: buf0 (k2) published
    LD4(gBf, k3, 1, fA0, fA1, fA2, fA3); VMW("4");
    CW(dB1, 0, fB0, fB1, fB2, fB3);
    BARX();
    RD_A0(rA0); RD_B01(rB0, b01a); SB0();
    MFQ(4, 0, af1, b01b);
  }

  // ---- epilogue: tiles 30 (buf0) and 31 (buf1); finish staging k31.A
  // e1: W k31.Bh1(A) / L k31.Ah0->B
  LD4(gAf, NKT - 1, 0, fB0, fB1, fB2, fB3); VMW("4");
  CW(dB1, 1, fA0, fA1, fA2, fA3);
  RD_B23(rB0); SB0();
  BARX(); LGKMW("4"); MFQ(0, 0, af0, b01a);
  // e2: W k31.Ah0(B) / L k31.Ah1->A
  LD4(gAf, NKT - 1, 1, fA0, fA1, fA2, fA3); VMW("4");
  CW(dA1, 0, fB0, fB1, fB2, fB3);
  RD_A1(rA0); SB0();
  BARX(); LGKMW("8"); MFQ(0, 2, af0, b23);
  // e3: W k31.Ah1(A); vm drained
  VMW("0");
  CW(dA1, 1, fA0, fA1, fA2, fA3);
  BARX(); LGKMW("0"); MFQ(4, 2, af1, b23);
  // e4: buf1 (k31) published
  BARX();
  RD_A0(rA1); RD_B01(rB1, b01b); SB0();
  MFQ(4, 0, af1, b01a);
  // e5
  RD_B23(rB1); SB0();
  BARX(); LGKMW("4"); MFQ(0, 0, af0, b01b);
  // e6
  RD_A1(rA1); SB0();
  BARX(); LGKMW("8"); MFQ(0, 2, af0, b23);
  // e7
  BARX(); LGKMW("0"); MFQ(4, 2, af1, b23);
  // e8
  MFQ(4, 0, af1, b01b);

  // ---- fused epilogue: +b, groupnorm over 8 consecutive n, min over n per m
  float colmin[4] = {3.4e38f, 3.4e38f, 3.4e38f, 3.4e38f};
#pragma unroll
  for (int i = 0; i < 8; ++i) {
    const float* bp = bgemm + nBase + wr * 128 + i * 16 + q * 4;
    float b0 = bp[0], b1 = bp[1], b2 = bp[2], b3 = bp[3];
#pragma unroll
    for (int j = 0; j < 4; ++j) {
      float v0 = acc[i][j][0] + b0;
      float v1 = acc[i][j][1] + b1;
      float v2 = acc[i][j][2] + b2;
      float v3 = acc[i][j][3] + b3;
      float s  = (v0 + v1) + (v2 + v3);
      float ss = (v0 * v0 + v1 * v1) + (v2 * v2 + v3 * v3);
      // partner quad (lane^16) holds the other 4 n's of this group of 8
      s  += __shfl_xor(s, 16);
      ss += __shfl_xor(ss, 16);
      float mean = s * 0.125f;
      float var  = ss * 0.125f - mean * mean;
      float inv  = rsqrtf(var + 1e-5f);          // inv > 0, so min commutes
      float mndev = fminf(fminf(v0, v1), fminf(v2, v3)) - mean;
      colmin[j] = fminf(colmin[j], mndev * inv);
    }
  }
#pragma unroll
  for (int j = 0; j < 4; ++j) {
    float m0 = colmin[j];
    m0 = fminf(m0, __shfl_xor(m0, 16));
    m0 = fminf(m0, __shfl_xor(m0, 32));
    colmin[j] = m0;
  }
  // LDS tiles are dead now; reuse the front of sA for the 2x256 partial mins.
  float* sm = (float*)sA;
  __syncthreads();
  if (q == 0) {
#pragma unroll
    for (int j = 0; j < 4; ++j)
      sm[wr * 256 + wc * 64 + j * 16 + c] = colmin[j];
  }
  __syncthreads();
  if (tid < 256) {
    float p = fminf(sm[tid], sm[256 + tid]);
    pmin[(size_t)(mBase + tid) * NT_N + nTile] = p;   // one writer per slot
  }
}

// ---------------- Kernel 2: out[m, n] = rowmin[m] + bias[n] -------------------
// One wave per row (4 rows/block, 2048 blocks); no LDS/sync; nontemporal
// stores (via native clang vector type) for the 128 MB write-only stream.
__global__ __launch_bounds__(256) void out_kernel(
    const float* __restrict__ pmin, const float* __restrict__ bias,
    float* __restrict__ out) {
  const int wv   = threadIdx.x >> 6;
  const int lane = threadIdx.x & 63;
  const int m = blockIdx.x * 4 + wv;
  float v = (lane < NT_N) ? pmin[(size_t)m * NT_N + lane] : 3.4e38f;
  v = fminf(v, __shfl_xor(v, 1));
  v = fminf(v, __shfl_xor(v, 2));
  v = fminf(v, __shfl_xor(v, 4));
  v = fminf(v, __shfl_xor(v, 8));
  const float rmin = __shfl(v, 0);
  const floatx4* b4 = (const floatx4*)bias;
  floatx4* o4 = (floatx4*)(out + (size_t)m * N_DIM);
#pragma unroll
  for (int it = 0; it < 16; ++it) {
    int idx2 = it * 64 + lane;
    floatx4 bb = b4[idx2];
    floatx4 ov = bb + rmin;
    __builtin_nontemporal_store(ov, &o4[idx2]);
  }
}

extern "C" void kernel_launch(void* const* d_in, const int* in_sizes, int n_in,
                              void* d_out, int out_size, void* d_ws, size_t ws_size,
                              hipStream_t stream) {
  const float* x    = (const float*)d_in[0];
  const float* W    = (const float*)d_in[1];
  const float* b    = (const float*)d_in[2];
  const float* bias = (const float*)d_in[3];
  float* out = (float*)d_out;
  float* pmin = (float*)d_ws;  // 8192 * 16 * 4 = 512 KiB of workspace

  gemm_gn_min<<<NT_M * NT_N, 512, 0, stream>>>(x, W, b, pmin);
  out_kernel<<<M_DIM / 4, 256, 0, stream>>>(pmin, bias, out);
}

// Round 10
// 361.495 us; speedup vs baseline: 1.6977x; 1.6977x over previous
//
#include <hip/hip_runtime.h>
#include <hip/hip_bf16.h>
#include <stdint.h>

#define M_DIM 8192
#define K_DIM 2048
#define N_DIM 4096
#define BT 256
#define NT_M (M_DIM / BT)   // 32 m-tiles
#define NT_N (N_DIM / BT)   // 16 n-tiles
#define NKT (K_DIM / 64)    // 32 K-tiles of BK=64

typedef __hip_bfloat16 bf16;
typedef __attribute__((ext_vector_type(8))) short bf16x8;
typedef __attribute__((ext_vector_type(4))) float floatx4;

// ---------------- Kernel 1: 256x256 8-phase GEMM (C^T) + GN + min, fused cvt --
// Register-budget-safe fusion (512-thr block => hard 256 unified regs/wave):
// frag banks shrunk 112->64 by single-bank af/b01/b23 with quadrant order
// (A0xb01, A0xb23, A1xb23, A1xb01) and post-MFQ bank reloads (reg anti-dep
// keeps them after the consuming MFMAs; asm lgkm fences pin phase windows).
// Staging: LD4 fp32 (1-phase-ahead, A/B ping-pong banks, VMW(4)) -> cvt ->
// 2x ds_write_b128. Gates = LGKMW(2): confirm all operand reads, leave own 2
// writes in flight (DS retires in order); writes drain at next gate, >=1
// barrier before first cross-wave reader (full ledger re-audited).

#define BARX() __builtin_amdgcn_s_barrier()
#define SB0()  __builtin_amdgcn_sched_barrier(0)
#define LGKMW(n) do { asm volatile("s_waitcnt lgkmcnt(" n ")" ::: "memory"); \
                      __builtin_amdgcn_sched_barrier(0); } while (0)
#define VMW(n)   do { asm volatile("s_waitcnt vmcnt(" n ")" ::: "memory"); \
                      __builtin_amdgcn_sched_barrier(0); } while (0)

// load one half-tile slice (this wave's 16 rows x 64k, fp32): 4 dwordx4
#define LD4(gp, kt, hh, R0, R1, R2, R3) do { \
  const float* _p = (gp) + ((size_t)(hh) * 128) * K_DIM + (size_t)(kt) * 64; \
  R0 = *(const floatx4*)(_p); \
  R1 = *(const floatx4*)(_p + 4); \
  R2 = *(const floatx4*)(_p + 8 * K_DIM); \
  R3 = *(const floatx4*)(_p + 8 * K_DIM + 4); \
} while (0)

// convert one staged half-tile slice to bf16, write to LDS (linear dest map)
#define CW(dp, hh, R0, R1, R2, R3) do { \
  union { bf16 h[8]; bf16x8 v; } _o0, _o1; \
  _o0.h[0] = __float2bfloat16(R0[0]); _o0.h[1] = __float2bfloat16(R0[1]); \
  _o0.h[2] = __float2bfloat16(R0[2]); _o0.h[3] = __float2bfloat16(R0[3]); \
  _o0.h[4] = __float2bfloat16(R1[0]); _o0.h[5] = __float2bfloat16(R1[1]); \
  _o0.h[6] = __float2bfloat16(R1[2]); _o0.h[7] = __float2bfloat16(R1[3]); \
  _o1.h[0] = __float2bfloat16(R2[0]); _o1.h[1] = __float2bfloat16(R2[1]); \
  _o1.h[2] = __float2bfloat16(R2[2]); _o1.h[3] = __float2bfloat16(R2[3]); \
  _o1.h[4] = __float2bfloat16(R3[0]); _o1.h[5] = __float2bfloat16(R3[1]); \
  _o1.h[6] = __float2bfloat16(R3[2]); _o1.h[7] = __float2bfloat16(R3[3]); \
  *(bf16x8*)((dp) + (hh) * 8192 + lane * 8) = _o0.v; \
  *(bf16x8*)((dp) + (hh) * 8192 + 512 + lane * 8) = _o1.v; \
} while (0)

// frag reads into the SINGLE banks; swk* carries the XOR bank swizzle
#define RD_A0(rp) do { _Pragma("unroll") for (int i2 = 0; i2 < 4; ++i2) { \
  af[i2][0] = *(const bf16x8*)((rp) + (i2 * 16) * 64 + swk0); \
  af[i2][1] = *(const bf16x8*)((rp) + (i2 * 16) * 64 + swk1); } } while (0)
#define RD_A1(rp) do { _Pragma("unroll") for (int i2 = 0; i2 < 4; ++i2) { \
  af[i2][0] = *(const bf16x8*)((rp) + (64 + i2 * 16) * 64 + swk0); \
  af[i2][1] = *(const bf16x8*)((rp) + (64 + i2 * 16) * 64 + swk1); } } while (0)
#define RD_B01(rp) do { _Pragma("unroll") for (int j2 = 0; j2 < 2; ++j2) { \
  b01[j2][0] = *(const bf16x8*)((rp) + (j2 * 16) * 64 + swk0); \
  b01[j2][1] = *(const bf16x8*)((rp) + (j2 * 16) * 64 + swk1); } } while (0)
#define RD_B23(rp) do { _Pragma("unroll") for (int j2 = 0; j2 < 2; ++j2) { \
  b23[j2][0] = *(const bf16x8*)((rp) + ((2 + j2) * 16) * 64 + swk0); \
  b23[j2][1] = *(const bf16x8*)((rp) + ((2 + j2) * 16) * 64 + swk1); } } while (0)

#define MFQ(i0, j0, A, B) do { \
  __builtin_amdgcn_s_setprio(1); \
  _Pragma("unroll") for (int i2 = 0; i2 < 4; ++i2) \
  _Pragma("unroll") for (int j2 = 0; j2 < 2; ++j2) { \
    acc[(i0) + i2][(j0) + j2] = __builtin_amdgcn_mfma_f32_16x16x32_bf16( \
        A[i2][0], B[j2][0], acc[(i0) + i2][(j0) + j2], 0, 0, 0); \
    acc[(i0) + i2][(j0) + j2] = __builtin_amdgcn_mfma_f32_16x16x32_bf16( \
        A[i2][1], B[j2][1], acc[(i0) + i2][(j0) + j2], 0, 0, 0); } \
  __builtin_amdgcn_s_setprio(0); } while (0)

__global__ __launch_bounds__(512) void gemm_gn_min(
    const float* __restrict__ x, const float* __restrict__ W,
    const float* __restrict__ bgemm, float* __restrict__ pmin) {
  __shared__ bf16 sA[32768];   // [2][256*64] W tiles (A-operand), 64 KiB
  __shared__ bf16 sB[32768];   // [2][256*64] x tiles (B-operand), 64 KiB

  const int tid  = threadIdx.x;
  const int lane = tid & 63;
  const int wid  = tid >> 6;      // 0..7
  const int wr   = wid >> 2;      // n-half (0..1): rows wr*128..+127
  const int wc   = wid & 3;       // m-quarter (0..3): cols wc*64..+63
  const int q    = lane >> 4;     // quad 0..3
  const int c    = lane & 15;

  const int mTile = blockIdx.x & (NT_M - 1);
  const int nTile = blockIdx.x >> 5;
  const int mBase = mTile * BT;
  const int nBase = nTile * BT;

  // staging map: lane -> (row-in-8-chunk, xor-swizzled k-chunk on GLOBAL col)
  const int ldRow = lane >> 3;
  const int swz   = ((lane & 7) ^ ldRow) * 8;
  // read-side swizzle (chunk = (ks*4+q) ^ (row&7); row&7 == c&7 here)
  const int swk0 = (q ^ (c & 7)) * 8;
  const int swk1 = ((4 + q) ^ (c & 7)) * 8;

  // per-wave fp32 staging bases (wave covers rows wid*16 + ldRow + {0,8})
  const float* gAf = W + (size_t)(nBase + wid * 16 + ldRow) * K_DIM + swz;
  const float* gBf = x + (size_t)(mBase + wid * 16 + ldRow) * K_DIM + swz;
  // per-wave LDS dest bases: buf0 (dA0/dB0) and buf1 (dA1/dB1)
  bf16* dA0 = sA + wid * 1024;
  bf16* dB0 = sB + wid * 1024;
  bf16* dA1 = dA0 + 16384;
  bf16* dB1 = dB0 + 16384;
  // per-lane LDS read bases
  const bf16* rA0 = sA + (wr * 128 + c) * 64;
  const bf16* rA1 = rA0 + 16384;
  const bf16* rB0 = sB + (wc * 64 + c) * 64;
  const bf16* rB1 = rB0 + 16384;

  floatx4 acc[8][4];
#pragma unroll
  for (int i = 0; i < 8; ++i)
#pragma unroll
    for (int j = 0; j < 4; ++j) acc[i][j] = (floatx4){0.f, 0.f, 0.f, 0.f};

  // SINGLE frag banks (64 regs) + fp32 staging ping-pong banks (32 regs)
  bf16x8 af[4][2], b01[2][2], b23[2][2];
  floatx4 fA0, fA1, fA2, fA3, fB0, fB1, fB2, fB3;

  // ---- prologue: stage k0 (4 halves) + k1.Bh0; leave LD4(k1.Bh1) in bank A
  LD4(gBf, 0, 0, fA0, fA1, fA2, fA3);
  LD4(gBf, 0, 1, fB0, fB1, fB2, fB3);
  VMW("4"); CW(dB0, 0, fA0, fA1, fA2, fA3);
  LD4(gAf, 0, 0, fA0, fA1, fA2, fA3);
  VMW("4"); CW(dB0, 1, fB0, fB1, fB2, fB3);
  LD4(gAf, 0, 1, fB0, fB1, fB2, fB3);
  VMW("4"); CW(dA0, 0, fA0, fA1, fA2, fA3);
  LD4(gBf, 1, 0, fA0, fA1, fA2, fA3);
  VMW("4"); CW(dA0, 1, fB0, fB1, fB2, fB3);
  VMW("0"); CW(dB1, 0, fA0, fA1, fA2, fA3);
  LD4(gBf, 1, 1, fA0, fA1, fA2, fA3);   // k1.Bh1 -> A (4 outstanding)
  LGKMW("0");
  BARX();
  RD_A0(rA0); RD_B01(rB0); RD_B23(rB0); SB0();   // k0 frags: 16 reads

  // ---- main loop: p1-4 compute k0 (buf0), p5-8 k1 (buf1). Quadrants per
  // tile: Q1(0,0)=A0xb01 Q2(0,2)=A0xb23 Q3(4,2)=A1xb23 Q4(4,0)=A1xb01.
  // Staging W(phase)/L(next): p1 Wk1.Bh1/Lk1.Ah0, p2 Wk1.Ah0/Lk1.Ah1,
  // p3 Wk1.Ah1/Lk2.Bh0, p4 Wk2.Bh0/Lk2.Bh1, p5 Wk2.Bh1/Lk2.Ah0,
  // p6 Wk2.Ah0/Lk2.Ah1, p7 Wk2.Ah1/Lk3.Bh0, p8 Wk3.Bh0/Lk3.Bh1.
  // Post-MFQ reloads: p2 af<-A1(k0), p3 b23<-k1, p4 af<-A0(k1)+b01<-k1,
  // p6 af<-A1(k1), p7 b23<-k2, p8 af<-A0(k2)+b01<-k2.
#pragma unroll 1
  for (int i = 0; i < NKT / 2 - 1; ++i) {
    const int k1 = 2 * i + 1, k2 = 2 * i + 2, k3 = 2 * i + 3;
    // p1
    LD4(gAf, k1, 0, fB0, fB1, fB2, fB3); VMW("4");
    CW(dB1, 1, fA0, fA1, fA2, fA3);
    BARX(); LGKMW("2"); MFQ(0, 0, af, b01);
    // p2
    LD4(gAf, k1, 1, fA0, fA1, fA2, fA3); VMW("4");
    CW(dA1, 0, fB0, fB1, fB2, fB3);
    BARX(); LGKMW("2"); MFQ(0, 2, af, b23);
    RD_A1(rA0); SB0();
    // p3
    LD4(gBf, k2, 0, fB0, fB1, fB2, fB3); VMW("4");
    CW(dA1, 1, fA0, fA1, fA2, fA3);
    BARX(); LGKMW("2"); MFQ(4, 2, af, b23);
    RD_B23(rB1); SB0();
    // p4
    LD4(gBf, k2, 1, fA0, fA1, fA2, fA3); VMW("4");
    CW(dB0, 0, fB0, fB1, fB2, fB3);
    BARX(); LGKMW("2"); MFQ(4, 0, af, b01);
    RD_A0(rA1); RD_B01(rB1); SB0();
    // p5
    LD4(gAf, k2, 0, fB0, fB1, fB2, fB3); VMW("4");
    CW(dB0, 1, fA0, fA1, fA2, fA3);
    BARX(); LGKMW("2"); MFQ(0, 0, af, b01);
    // p6
    LD4(gAf, k2, 1, fA0, fA1, fA2, fA3); VMW("4");
    CW(dA0, 0, fB0, fB1, fB2, fB3);
    BARX(); LGKMW("2"); MFQ(0, 2, af, b23);
    RD_A1(rA1); SB0();
    // p7
    LD4(gBf, k3, 0, fB0, fB1, fB2, fB3); VMW("4");
    CW(dA0, 1, fA0, fA1, fA2, fA3);
    BARX(); LGKMW("2"); MFQ(4, 2, af, b23);
    RD_B23(rB0); SB0();
    // p8
    LD4(gBf, k3, 1, fA0, fA1, fA2, fA3); VMW("4");
    CW(dB1, 0, fB0, fB1, fB2, fB3);
    BARX(); LGKMW("2"); MFQ(4, 0, af, b01);
    RD_A0(rA0); RD_B01(rB0); SB0();
  }

  // ---- epilogue: tiles 30 (buf0) / 31 (buf1); finish staging k31.A
  // e1
  LD4(gAf, NKT - 1, 0, fB0, fB1, fB2, fB3); VMW("4");
  CW(dB1, 1, fA0, fA1, fA2, fA3);
  BARX(); LGKMW("2"); MFQ(0, 0, af, b01);
  // e2
  LD4(gAf, NKT - 1, 1, fA0, fA1, fA2, fA3); VMW("4");
  CW(dA1, 0, fB0, fB1, fB2, fB3);
  BARX(); LGKMW("2"); MFQ(0, 2, af, b23);
  RD_A1(rA0); SB0();
  // e3: drain loads, write k31.Ah1
  VMW("0");
  CW(dA1, 1, fA0, fA1, fA2, fA3);
  BARX(); LGKMW("2"); MFQ(4, 2, af, b23);
  RD_B23(rB1); SB0();
  // e4
  BARX(); LGKMW("0"); MFQ(4, 0, af, b01);
  RD_A0(rA1); RD_B01(rB1); SB0();
  // e5
  BARX(); LGKMW("0"); MFQ(0, 0, af, b01);
  // e6
  BARX(); LGKMW("0"); MFQ(0, 2, af, b23);
  RD_A1(rA1); SB0();
  // e7
  BARX(); LGKMW("0"); MFQ(4, 2, af, b23);
  // e8
  BARX(); LGKMW("0"); MFQ(4, 0, af, b01);

  // ---- fused epilogue: +b, groupnorm over 8 consecutive n, min over n per m
  float colmin[4] = {3.4e38f, 3.4e38f, 3.4e38f, 3.4e38f};
#pragma unroll
  for (int i = 0; i < 8; ++i) {
    const float* bp = bgemm + nBase + wr * 128 + i * 16 + q * 4;
    float b0 = bp[0], b1 = bp[1], b2 = bp[2], b3 = bp[3];
#pragma unroll
    for (int j = 0; j < 4; ++j) {
      float v0 = acc[i][j][0] + b0;
      float v1 = acc[i][j][1] + b1;
      float v2 = acc[i][j][2] + b2;
      float v3 = acc[i][j][3] + b3;
      float s  = (v0 + v1) + (v2 + v3);
      float ss = (v0 * v0 + v1 * v1) + (v2 * v2 + v3 * v3);
      // partner quad (lane^16) holds the other 4 n's of this group of 8
      s  += __shfl_xor(s, 16);
      ss += __shfl_xor(ss, 16);
      float mean = s * 0.125f;
      float var  = ss * 0.125f - mean * mean;
      float inv  = rsqrtf(var + 1e-5f);          // inv > 0, so min commutes
      float mndev = fminf(fminf(v0, v1), fminf(v2, v3)) - mean;
      colmin[j] = fminf(colmin[j], mndev * inv);
    }
  }
#pragma unroll
  for (int j = 0; j < 4; ++j) {
    float m0 = colmin[j];
    m0 = fminf(m0, __shfl_xor(m0, 16));
    m0 = fminf(m0, __shfl_xor(m0, 32));
    colmin[j] = m0;
  }
  // LDS tiles are dead now; reuse the front of sA for the 2x256 partial mins.
  float* sm = (float*)sA;
  __syncthreads();
  if (q == 0) {
#pragma unroll
    for (int j = 0; j < 4; ++j)
      sm[wr * 256 + wc * 64 + j * 16 + c] = colmin[j];
  }
  __syncthreads();
  if (tid < 256) {
    float p = fminf(sm[tid], sm[256 + tid]);
    pmin[(size_t)(mBase + tid) * NT_N + nTile] = p;   // one writer per slot
  }
}

// ---------------- Kernel 2: out[m, n] = rowmin[m] + bias[n] -------------------
// One wave per row (4 rows/block, 2048 blocks); no LDS/sync; nontemporal
// stores (via native clang vector type) for the 128 MB write-only stream.
__global__ __launch_bounds__(256) void out_kernel(
    const float* __restrict__ pmin, const float* __restrict__ bias,
    float* __restrict__ out) {
  const int wv   = threadIdx.x >> 6;
  const int lane = threadIdx.x & 63;
  const int m = blockIdx.x * 4 + wv;
  float v = (lane < NT_N) ? pmin[(size_t)m * NT_N + lane] : 3.4e38f;
  v = fminf(v, __shfl_xor(v, 1));
  v = fminf(v, __shfl_xor(v, 2));
  v = fminf(v, __shfl_xor(v, 4));
  v = fminf(v, __shfl_xor(v, 8));
  const float rmin = __shfl(v, 0);
  const floatx4* b4 = (const floatx4*)bias;
  floatx4* o4 = (floatx4*)(out + (size_t)m * N_DIM);
#pragma unroll
  for (int it = 0; it < 16; ++it) {
    int idx2 = it * 64 + lane;
    floatx4 bb = b4[idx2];
    floatx4 ov = bb + rmin;
    __builtin_nontemporal_store(ov, &o4[idx2]);
  }
}

extern "C" void kernel_launch(void* const* d_in, const int* in_sizes, int n_in,
                              void* d_out, int out_size, void* d_ws, size_t ws_size,
                              hipStream_t stream) {
  const float* x    = (const float*)d_in[0];
  const float* W    = (const float*)d_in[1];
  const float* b    = (const float*)d_in[2];
  const float* bias = (const float*)d_in[3];
  float* out = (float*)d_out;
  float* pmin = (float*)d_ws;  // 8192 * 16 * 4 = 512 KiB of workspace

  gemm_gn_min<<<NT_M * NT_N, 512, 0, stream>>>(x, W, b, pmin);
  out_kernel<<<M_DIM / 4, 256, 0, stream>>>(pmin, bias, out);
}